// Round 16
// baseline (198.076 us; speedup 1.0000x reference)
//
#include <hip/hip_runtime.h>

// B=2, L=2048, H=16, D=64 (DIM=1024). fp32 I/O, bf16 MFMA internals, fp32 accum.
// R27 (on R26, session best 195.4us): (1) drop the post-vmcnt sched_barrier(0)
// in gemm_qkv/attn/gemm_out — the "memory" clobber already orders ds_reads
// after the wait; freeing the scheduler lets addr-calc VALU fill the stall
// window (the pre-vmcnt barrier pinning staging issue is kept). (2) attn lacc
// ones-MFMA -> VALU lsum (R12 epilogue ported to 4-g layout): R13's A/B
// measured the MFMA variant ~1.7us worse; removes 8 MFMA/kt/wave from the
// critical matrix pipe. R26 grid facts kept: gemm_qkv 128^2/768 blocks = 3/CU
// (only clean divisor config; 256^2 = 192 blocks idles 25% of CUs), gemm_out
// XCD-swizzled 1-D grid.

typedef __bf16 bf16x8 __attribute__((ext_vector_type(8)));
typedef __bf16 bf16x2 __attribute__((ext_vector_type(2)));
typedef float f32x4 __attribute__((ext_vector_type(4)));

#define QSCALE 0.1803368802f  // 0.125 * log2(e)

__device__ __forceinline__ float bf2f(unsigned short u) {
  unsigned int v = ((unsigned int)u) << 16;
  float f;
  __builtin_memcpy(&f, &v, 4);
  return f;
}
__device__ __forceinline__ unsigned short f2bf(float f) {
  unsigned int v;
  __builtin_memcpy(&v, &f, 4);
  v += 0x7fffu + ((v >> 16) & 1u);
  return (unsigned short)(v >> 16);
}
__device__ __forceinline__ unsigned short f2bf_hw(float f) {
  __bf16 h = (__bf16)f;
  unsigned short u;
  __builtin_memcpy(&u, &h, 2);
  return u;
}
__device__ __forceinline__ unsigned int pack2(float a, float b) {
  bf16x2 t;
  t[0] = (__bf16)a;
  t[1] = (__bf16)b;
  unsigned int u;
  __builtin_memcpy(&u, &t, 4);
  return u;
}
__device__ __forceinline__ void gl_lds16(const unsigned short* g, unsigned short* l) {
  __builtin_amdgcn_global_load_lds(
      (const __attribute__((address_space(1))) unsigned int*)g,
      (__attribute__((address_space(3))) unsigned int*)l, 16, 0, 0);
}

// ---------------- fused prep: cvt_x + transposes + RoPE LUT ---------------------
__global__ __launch_bounds__(256) void prep(
    const float* __restrict__ x, const float* __restrict__ W_qkv,
    const float* __restrict__ W_out, const int* __restrict__ positions,
    unsigned short* __restrict__ xb,
    unsigned short* __restrict__ Wt_qkv, unsigned short* __restrict__ Wt_out,
    float2* __restrict__ lut) {
  __shared__ float tile[64][65];
  const int bid = blockIdx.x, t = threadIdx.x;
  if (bid < 4096) {  // x fp32 -> bf16
    int i = (bid * 256 + t) * 4;
    float4 v = *reinterpret_cast<const float4*>(x + i);
    ushort4 o;
    o.x = f2bf(v.x); o.y = f2bf(v.y); o.z = f2bf(v.z); o.w = f2bf(v.w);
    *reinterpret_cast<ushort4*>(xb + i) = o;
    return;
  }
  if (bid >= 5120) {  // RoPE LUT: 4096 rows x 32 dpairs
    int idx = (bid - 5120) * 256 + t;
    int m = idx >> 5, p = idx & 31;
    float pos = (float)positions[m];
    float invf = __builtin_amdgcn_exp2f(-(float)(2 * p) * (13.2877124f / 64.0f));
    float rev = pos * invf * 0.15915494f;
    rev -= floorf(rev);
    lut[idx] = make_float2(__builtin_amdgcn_cosf(rev), __builtin_amdgcn_sinf(rev));
    return;
  }
  const float* W; unsigned short* Wt; int Nd, bn, bk;
  if (bid < 4864) {
    int id = bid - 4096; W = W_qkv; Wt = Wt_qkv; Nd = 3072; bn = id % 48; bk = id / 48;
  } else {
    int id = bid - 4864; W = W_out; Wt = Wt_out; Nd = 1024; bn = id % 16; bk = id / 16;
  }
  const int Kd = 1024;
#pragma unroll
  for (int i = 0; i < 16; i++) {
    int idx = i * 256 + t;
    int k = idx >> 6, n = idx & 63;
    tile[k][n] = W[(size_t)(bk * 64 + k) * Nd + bn * 64 + n];
  }
  __syncthreads();
#pragma unroll
  for (int i = 0; i < 16; i++) {
    int idx = i * 256 + t;
    int n = idx >> 6, k = idx & 63;
    Wt[(size_t)(bn * 64 + n) * Kd + bk * 64 + k] = f2bf(tile[k][n]);
  }
}

// ---------------- QKV GEMM 128x128 dbuf + counted vmcnt (2 heads/block) ---------
// grid (24, 32): bn<8 Q (heads 2bn,2bn+1), 8..15 K, 16..23 V.
// 4 waves in 2x2; each wave 64 rows x 64 cols (= one head's columns).
__global__ __launch_bounds__(256, 4) void gemm_qkv(
    const unsigned short* __restrict__ A,
    const unsigned short* __restrict__ Bt,
    const float* __restrict__ qn_w, const float* __restrict__ kn_w,
    const float2* __restrict__ lut,
    unsigned short* __restrict__ Qr,
    unsigned short* __restrict__ Kr,
    unsigned short* __restrict__ Vt, int K) {
  __shared__ __align__(16) unsigned short As[2][128 * 32];
  __shared__ __align__(16) unsigned short Bs[2][128 * 32];
  const int tid = threadIdx.x;
  const int lane = tid & 63, wid = tid >> 6;
  const int quad = lane >> 4, l16 = lane & 15;
  const int wr = wid >> 1, wc = wid & 1;
  const int bn = blockIdx.x, bm = blockIdx.y;
  const unsigned short* Ab = A + (size_t)bm * 128 * K;
  const unsigned short* Bb = Bt + (size_t)bn * 128 * K;

  f32x4 acc[4][4] = {};

  const int c0 = tid, c1 = tid + 256;
  const int ar0 = c0 >> 2, ag0 = ((c0 & 3) ^ ((ar0 >> 1) & 3)) * 8;
  const int ar1 = c1 >> 2, ag1 = ((c1 & 3) ^ ((ar1 >> 1) & 3)) * 8;

  gl_lds16(Ab + (size_t)ar0 * K + ag0, &As[0][c0 * 8]);
  gl_lds16(Ab + (size_t)ar1 * K + ag1, &As[0][c1 * 8]);
  gl_lds16(Bb + (size_t)ar0 * K + ag0, &Bs[0][c0 * 8]);
  gl_lds16(Bb + (size_t)ar1 * K + ag1, &Bs[0][c1 * 8]);

  const int iters = K >> 5;
  for (int it = 0; it < iters; it++) {
    const int cur = it & 1;
    __builtin_amdgcn_s_barrier();
    if (it + 1 < iters) {
      const int k0 = (it + 1) << 5, nb = cur ^ 1;
      gl_lds16(Ab + (size_t)ar0 * K + k0 + ag0, &As[nb][c0 * 8]);
      gl_lds16(Ab + (size_t)ar1 * K + k0 + ag1, &As[nb][c1 * 8]);
      gl_lds16(Bb + (size_t)ar0 * K + k0 + ag0, &Bs[nb][c0 * 8]);
      gl_lds16(Bb + (size_t)ar1 * K + k0 + ag1, &Bs[nb][c1 * 8]);
      __builtin_amdgcn_sched_barrier(0);
      asm volatile("s_waitcnt vmcnt(4)" ::: "memory");
    } else {
      __builtin_amdgcn_sched_barrier(0);
      asm volatile("s_waitcnt vmcnt(0)" ::: "memory");
    }
    __builtin_amdgcn_s_setprio(1);
    const unsigned short* Ac = As[cur];
    const unsigned short* Bc = Bs[cur];
    bf16x8 af[4], bfr[4];
#pragma unroll
    for (int i = 0; i < 4; i++) {
      int m = wr * 64 + i * 16 + l16;
      af[i] = *reinterpret_cast<const bf16x8*>(&Ac[m * 32 + ((quad ^ ((m >> 1) & 3)) * 8)]);
    }
#pragma unroll
    for (int j = 0; j < 4; j++) {
      int n = wc * 64 + j * 16 + l16;
      bfr[j] = *reinterpret_cast<const bf16x8*>(&Bc[n * 32 + ((quad ^ ((n >> 1) & 3)) * 8)]);
    }
#pragma unroll
    for (int i = 0; i < 4; i++)
#pragma unroll
      for (int j = 0; j < 4; j++)
        acc[i][j] = __builtin_amdgcn_mfma_f32_16x16x32_bf16(af[i], bfr[j], acc[i][j], 0, 0, 0);
    __builtin_amdgcn_s_setprio(0);
  }

  const int sec = bn >> 3;
  const int h = (bn & 7) * 2 + wc;
  const int b = bm >> 4;
  if (sec < 2) {
    // -------- fused LN + RoPE (rows wave-local; 16 rows/thread) --------
    const float* gw = sec ? kn_w : qn_w;
    unsigned short* dst = sec ? Kr : Qr;
    const float oscale = sec ? 1.0f : QSCALE;  // Q pre-scaled for attn's exp2
    float w4[4];
#pragma unroll
    for (int j = 0; j < 4; j++) w4[j] = gw[h * 64 + j * 16 + l16];
#pragma unroll
    for (int i = 0; i < 4; i++)
#pragma unroll
      for (int r = 0; r < 4; r++) {
        int m = bm * 128 + wr * 64 + i * 16 + quad * 4 + r;  // b*2048 + l
        int l = m & 2047;
        const float2* lrow = lut + m * 32;
        float2 cs4[4];
#pragma unroll
        for (int j = 0; j < 4; j++) cs4[j] = lrow[j * 8 + (l16 >> 1)];
        float sum = acc[i][0][r] + acc[i][1][r] + acc[i][2][r] + acc[i][3][r];
        float sq = acc[i][0][r] * acc[i][0][r] + acc[i][1][r] * acc[i][1][r] +
                   acc[i][2][r] * acc[i][2][r] + acc[i][3][r] * acc[i][3][r];
#pragma unroll
        for (int off = 1; off < 16; off <<= 1) {
          sum += __shfl_xor(sum, off);
          sq += __shfl_xor(sq, off);
        }
        float mu = sum * (1.0f / 64.0f);
        float var = sq * (1.0f / 64.0f) - mu * mu;
        float rs = rsqrtf(fmaxf(var, 0.0f) + 1e-6f);
#pragma unroll
        for (int j = 0; j < 4; j++) {
          float y = (acc[i][j][r] - mu) * rs * w4[j];
          float p = __shfl_xor(y, 1);
          float o = (l16 & 1) ? (y * cs4[j].x + p * cs4[j].y)
                              : (y * cs4[j].x - p * cs4[j].y);
          dst[((size_t)(b * 16 + h) * 2048 + l) * 64 + j * 16 + l16] = f2bf(o * oscale);
        }
      }
  } else {
    // -------- V: permuted scatter, packed 4-r uint2 stores --------
    // Contract with attn: within each 32-key group, actual row
    // (i&1)*16 + quad*4 + r is stored at quad*8 + (i&1)*4 + r.
#pragma unroll
    for (int i = 0; i < 4; i++) {
      int lp = (bm * 128 + wr * 64 + (i >> 1) * 32 + quad * 8 + (i & 1) * 4) & 2047;
#pragma unroll
      for (int j = 0; j < 4; j++) {
        int d = j * 16 + l16;
        uint2 v;
        v.x = pack2(acc[i][j][0], acc[i][j][1]);
        v.y = pack2(acc[i][j][2], acc[i][j][3]);
        *reinterpret_cast<uint2*>(&Vt[((size_t)(b * 16 + h) * 64 + d) * 2048 + lp]) = v;
      }
    }
  }
}

// ---------------- Flash attention: 4 waves x 64 q-rows, shared fragments --------
// R27: lacc ones-MFMA -> VALU lsum (R12 epilogue, wg*64 layout); -8 MFMA/kt/wave
// on the critical matrix pipe.
__global__ __launch_bounds__(256, 2) void attn_kernel(
    const unsigned short* __restrict__ Q,
    const unsigned short* __restrict__ K,
    const unsigned short* __restrict__ Vt,
    unsigned short* __restrict__ O) {
  __shared__ __align__(16) unsigned short Ks[2][2][64 * 64];  // [half][buf] 32KB
  __shared__ __align__(16) unsigned short Vs[2][2][64 * 64];  // 32KB

  int bid = blockIdx.x;
  int id = (bid & 7) * 64 + (bid >> 3);  // bijective XCD swizzle (512 % 8 == 0)
  const int qt = id & 15; id >>= 4;
  const int h = id & 15;  const int b = id >> 4;
  const int tid = threadIdx.x;
  const int lane = tid & 63, wid = tid >> 6;
  const int half = wid >> 1, wg = wid & 1;
  const int quad = lane >> 4, l16 = lane & 15;

  const unsigned short* Qb = Q + (size_t)(b * 16 + h) * 2048 * 64;
  const unsigned short* Kb = K + (size_t)(b * 16 + h) * 2048 * 64;
  const unsigned short* Vb = Vt + (size_t)(b * 16 + h) * 64 * 2048;

  const int qbase = qt * 128 + wg * 64;
  bf16x8 qf[4][2];
#pragma unroll
  for (int g = 0; g < 4; g++)
#pragma unroll
    for (int d = 0; d < 2; d++)
      qf[g][d] = *reinterpret_cast<const bf16x8*>(
          &Qb[(size_t)(qbase + g * 16 + l16) * 64 + d * 32 + quad * 8]);

  f32x4 o[4][4] = {};
  float lsum[4] = {0.f, 0.f, 0.f, 0.f};

  const int ltid = tid & 127;
  int cs[4], rs[4], gsw[4];
#pragma unroll
  for (int j = 0; j < 4; j++) {
    cs[j] = ltid + j * 128;
    rs[j] = cs[j] >> 3;
    gsw[j] = ((cs[j] & 7) ^ (rs[j] & 7)) * 8;
  }
  const int kb0 = half * 1024;

#pragma unroll
  for (int j = 0; j < 4; j++)
    gl_lds16(&Kb[(size_t)(kb0 + rs[j]) * 64 + gsw[j]], &Ks[half][0][cs[j] * 8]);
#pragma unroll
  for (int j = 0; j < 4; j++)
    gl_lds16(&Vb[(size_t)rs[j] * 2048 + kb0 + gsw[j]], &Vs[half][0][cs[j] * 8]);

  for (int kt = 0; kt < 16; kt++) {
    const int cur = kt & 1;
    __builtin_amdgcn_s_barrier();
    if (kt + 1 < 16) {
      const int ko = kb0 + (kt + 1) * 64, nb = cur ^ 1;
#pragma unroll
      for (int j = 0; j < 4; j++)
        gl_lds16(&Kb[(size_t)(ko + rs[j]) * 64 + gsw[j]], &Ks[half][nb][cs[j] * 8]);
#pragma unroll
      for (int j = 0; j < 4; j++)
        gl_lds16(&Vb[(size_t)rs[j] * 2048 + ko + gsw[j]], &Vs[half][nb][cs[j] * 8]);
      __builtin_amdgcn_sched_barrier(0);
      asm volatile("s_waitcnt vmcnt(8)" ::: "memory");
    } else {
      __builtin_amdgcn_sched_barrier(0);
      asm volatile("s_waitcnt vmcnt(0)" ::: "memory");
    }
    const unsigned short* Kc = Ks[half][cur];
    const unsigned short* Vc = Vs[half][cur];

    __builtin_amdgcn_s_setprio(1);
    // ---- QK^T: kf read once per kg, consumed by all 4 q-groups ----
    f32x4 s4[4][4] = {};  // [g][kg]
#pragma unroll
    for (int kg = 0; kg < 4; kg++) {
      int row = kg * 16 + l16;
      bf16x8 kf0 = *reinterpret_cast<const bf16x8*>(
          &Kc[row * 64 + ((quad ^ (row & 7)) * 8)]);
      bf16x8 kf1 = *reinterpret_cast<const bf16x8*>(
          &Kc[row * 64 + (((4 + quad) ^ (row & 7)) * 8)]);
#pragma unroll
      for (int g = 0; g < 4; g++) {
        s4[g][kg] = __builtin_amdgcn_mfma_f32_16x16x32_bf16(kf0, qf[g][0], s4[g][kg], 0, 0, 0);
        s4[g][kg] = __builtin_amdgcn_mfma_f32_16x16x32_bf16(kf1, qf[g][1], s4[g][kg], 0, 0, 0);
      }
    }
    // ---- exp2 + VALU lsum + bf16 pack (s4 dies into pa) ----
    union u32x4v { unsigned int u[4]; bf16x8 v; };
    u32x4v pa[4][2];
#pragma unroll
    for (int g = 0; g < 4; g++) {
      float pv[4][4];
#pragma unroll
      for (int kg = 0; kg < 4; kg++)
#pragma unroll
        for (int r = 0; r < 4; r++) {
          float e = __builtin_amdgcn_exp2f(s4[g][kg][r]);  // Q pre-scaled 0.125*log2e
          pv[kg][r] = e;
          lsum[g] += e;
        }
#pragma unroll
      for (int c = 0; c < 2; c++) {
        pa[g][c].u[0] = pack2(pv[c * 2][0], pv[c * 2][1]);
        pa[g][c].u[1] = pack2(pv[c * 2][2], pv[c * 2][3]);
        pa[g][c].u[2] = pack2(pv[c * 2 + 1][0], pv[c * 2 + 1][1]);
        pa[g][c].u[3] = pack2(pv[c * 2 + 1][2], pv[c * 2 + 1][3]);
      }
    }
    // ---- PV: vfr read once per (c,i), consumed by all 4 q-groups ----
#pragma unroll
    for (int c = 0; c < 2; c++)
#pragma unroll
      for (int i = 0; i < 4; i++) {
        int row = i * 16 + l16;
        bf16x8 vfr = *reinterpret_cast<const bf16x8*>(
            &Vc[row * 64 + (((c * 4 + quad) ^ (row & 7)) * 8)]);
#pragma unroll
        for (int g = 0; g < 4; g++)
          o[g][i] = __builtin_amdgcn_mfma_f32_16x16x32_bf16(pa[g][c].v, vfr, o[g][i], 0, 0, 0);
      }
    __builtin_amdgcn_s_setprio(0);
  }

  // lsum currently per-lane partial over this wave's P columns; reduce to per-q.
#pragma unroll
  for (int g = 0; g < 4; g++) {
    lsum[g] += __shfl_xor(lsum[g], 16);
    lsum[g] += __shfl_xor(lsum[g], 32);
  }

  __syncthreads();
  float* Om = (float*)&Ks[0][0][0];  // 128x64 fp32 = 32 KB
  float* Lm = (float*)&Vs[0][0][0];
  if (half == 0) {
#pragma unroll
    for (int g = 0; g < 4; g++) {
#pragma unroll
      for (int i = 0; i < 4; i++)
#pragma unroll
        for (int r = 0; r < 4; r++)
          Om[(wg * 64 + g * 16 + quad * 4 + r) * 64 + i * 16 + l16] = o[g][i][r];
      if (quad == 0) Lm[wg * 64 + g * 16 + l16] = lsum[g];
    }
  }
  __syncthreads();
  if (half == 1) {
#pragma unroll
    for (int g = 0; g < 4; g++) {
      float lt = lsum[g] + Lm[wg * 64 + g * 16 + l16];
#pragma unroll
      for (int r = 0; r < 4; r++) {
        float inv = 1.0f / __shfl(lt, quad * 4 + r);
        int q = qbase + g * 16 + quad * 4 + r;
#pragma unroll
        for (int i = 0; i < 4; i++) {
          float sum = o[g][i][r] + Om[(wg * 64 + g * 16 + quad * 4 + r) * 64 + i * 16 + l16];
          O[((size_t)(b * 2048 + q)) * 1024 + h * 64 + i * 16 + l16] = f2bf_hw(sum * inv);
        }
      }
    }
  }
}

// ---------------- final GEMM 128x64 tiles, BK=64, dbuf + counted vmcnt ----------
// grid 512 (1-D) with XCD swizzle: id=(bid&7)*64+bid>>3, bm=id>>4, bn=id&15.
__global__ __launch_bounds__(256) void gemm_out(
    const unsigned short* __restrict__ A,
    const unsigned short* __restrict__ Bt,
    float* __restrict__ C, int M, int N, int K) {
  __shared__ __align__(16) unsigned short As[2][128 * 64];
  __shared__ __align__(16) unsigned short Bs[2][64 * 64];
  const int tid = threadIdx.x;
  const int lane = tid & 63, wid = tid >> 6;
  const int quad = lane >> 4, l16 = lane & 15;
  int bid = blockIdx.x;
  int id = (bid & 7) * 64 + (bid >> 3);  // bijective XCD swizzle (512 % 8 == 0)
  const int bn = id & 15, bm = id >> 4;  // consecutive ids share bm (A panel)
  const unsigned short* Ab = A + (size_t)bm * 128 * K;
  const unsigned short* Bb = Bt + (size_t)bn * 64 * K;

  f32x4 acc[2][4] = {};

  int arow[4], asrc[4];
#pragma unroll
  for (int t2 = 0; t2 < 4; t2++) {
    int s = t2 * 256 + tid;
    arow[t2] = s >> 3;
    asrc[t2] = (((s & 7) ^ (arow[t2] & 7)) * 8);
  }
  int brow[2], bsrc[2];
#pragma unroll
  for (int t2 = 0; t2 < 2; t2++) {
    int s = t2 * 256 + tid;
    brow[t2] = s >> 3;
    bsrc[t2] = (((s & 7) ^ (brow[t2] & 7)) * 8);
  }

#pragma unroll
  for (int t2 = 0; t2 < 4; t2++)
    gl_lds16(Ab + (size_t)arow[t2] * K + asrc[t2], &As[0][(t2 * 256 + tid) * 8]);
#pragma unroll
  for (int t2 = 0; t2 < 2; t2++)
    gl_lds16(Bb + (size_t)brow[t2] * K + bsrc[t2], &Bs[0][(t2 * 256 + tid) * 8]);

  const int iters = K >> 6;  // 16
  for (int it = 0; it < iters; it++) {
    const int cur = it & 1;
    __builtin_amdgcn_s_barrier();
    if (it + 1 < iters) {
      const int k0 = (it + 1) << 6, nb = cur ^ 1;
#pragma unroll
      for (int t2 = 0; t2 < 4; t2++)
        gl_lds16(Ab + (size_t)arow[t2] * K + k0 + asrc[t2], &As[nb][(t2 * 256 + tid) * 8]);
#pragma unroll
      for (int t2 = 0; t2 < 2; t2++)
        gl_lds16(Bb + (size_t)brow[t2] * K + k0 + bsrc[t2], &Bs[nb][(t2 * 256 + tid) * 8]);
      __builtin_amdgcn_sched_barrier(0);
      asm volatile("s_waitcnt vmcnt(6)" ::: "memory");
    } else {
      __builtin_amdgcn_sched_barrier(0);
      asm volatile("s_waitcnt vmcnt(0)" ::: "memory");
    }
    __builtin_amdgcn_s_setprio(1);
    const unsigned short* Ac = As[cur];
    const unsigned short* Bc = Bs[cur];
    bf16x8 af[2][2], bfr[4][2];
#pragma unroll
    for (int i = 0; i < 2; i++) {
      int m = wid * 32 + i * 16 + l16;
#pragma unroll
      for (int kk = 0; kk < 2; kk++)
        af[i][kk] = *reinterpret_cast<const bf16x8*>(
            &Ac[(m * 8 + ((kk * 4 + quad) ^ (m & 7))) * 8]);
    }
#pragma unroll
    for (int j = 0; j < 4; j++) {
      int n = j * 16 + l16;
#pragma unroll
      for (int kk = 0; kk < 2; kk++)
        bfr[j][kk] = *reinterpret_cast<const bf16x8*>(
            &Bc[(n * 8 + ((kk * 4 + quad) ^ (n & 7))) * 8]);
    }
#pragma unroll
    for (int kk = 0; kk < 2; kk++)
#pragma unroll
      for (int i = 0; i < 2; i++)
#pragma unroll
        for (int j = 0; j < 4; j++)
          acc[i][j] = __builtin_amdgcn_mfma_f32_16x16x32_bf16(af[i][kk], bfr[j][kk], acc[i][j], 0, 0, 0);
    __builtin_amdgcn_s_setprio(0);
  }
#pragma unroll
  for (int i = 0; i < 2; i++)
#pragma unroll
    for (int j = 0; j < 4; j++)
#pragma unroll
      for (int r = 0; r < 4; r++) {
        int m = bm * 128 + wid * 32 + i * 16 + quad * 4 + r;
        int n = bn * 64 + j * 16 + l16;
        C[(size_t)m * N + n] = acc[i][j][r];
      }
}

extern "C" void kernel_launch(void* const* d_in, const int* in_sizes, int n_in,
                              void* d_out, int out_size, void* d_ws, size_t ws_size,
                              hipStream_t stream) {
  (void)in_sizes; (void)n_in; (void)out_size; (void)ws_size;
  const float* x     = (const float*)d_in[0];
  const int*   pos   = (const int*)d_in[2];
  const float* W_qkv = (const float*)d_in[3];
  const float* W_out = (const float*)d_in[4];
  const float* qn_w  = (const float*)d_in[5];
  const float* kn_w  = (const float*)d_in[6];
  float*       out   = (float*)d_out;

  char* ws = (char*)d_ws;
  unsigned short* xb     = (unsigned short*)(ws);
  unsigned short* Qr     = (unsigned short*)(ws + 8388608);
  unsigned short* Kr     = (unsigned short*)(ws + 16777216);
  unsigned short* Vt     = (unsigned short*)(ws + 25165824);
  unsigned short* Wt_qkv = (unsigned short*)(ws + 33554432);
  unsigned short* Wt_out = (unsigned short*)(ws + 39845888);
  float2*         lut    = (float2*)(ws + 41943040);
  unsigned short* attn_o = xb;

  prep<<<5632, 256, 0, stream>>>(x, W_qkv, W_out, pos, xb, Wt_qkv, Wt_out, lut);
  gemm_qkv<<<dim3(24, 32), 256, 0, stream>>>(xb, Wt_qkv, qn_w, kn_w, lut, Qr, Kr, Vt, 1024);
  attn_kernel<<<512, 256, 0, stream>>>(Qr, Kr, Vt, attn_o);
  gemm_out<<<512, 256, 0, stream>>>(attn_o, Wt_out, out, 4096, 1024, 1024);
}

// Round 17
// 194.740 us; speedup vs baseline: 1.0171x; 1.0171x over previous
//
#include <hip/hip_runtime.h>

// B=2, L=2048, H=16, D=64 (DIM=1024). fp32 I/O, bf16 MFMA internals, fp32 accum.
// R28: split counted-vmcnt waits (finer T4) in all three MFMA kernels — wait
// only for the first-issued half of the current tile before reading its
// fragments, letting the rest complete under the reads:
//   gemm_qkv: vmcnt(6) -> af reads -> vmcnt(4) -> bfr + MFMA
//   gemm_out: vmcnt(8) -> af reads -> vmcnt(6) -> bfr + MFMA
//   attn:     vmcnt(12) -> QK^T + softmax + pack -> vmcnt(8) -> PV
// (attn's window is the big one: 32 MFMA + softmax cover cur's V-load tail.)
// Memory-clobbered asm pins ds_reads between the waits; strictly weaker waits,
// correctness unchanged. Rest identical to R27/R26 plateau composition.

typedef __bf16 bf16x8 __attribute__((ext_vector_type(8)));
typedef __bf16 bf16x2 __attribute__((ext_vector_type(2)));
typedef float f32x4 __attribute__((ext_vector_type(4)));

#define QSCALE 0.1803368802f  // 0.125 * log2(e)

__device__ __forceinline__ float bf2f(unsigned short u) {
  unsigned int v = ((unsigned int)u) << 16;
  float f;
  __builtin_memcpy(&f, &v, 4);
  return f;
}
__device__ __forceinline__ unsigned short f2bf(float f) {
  unsigned int v;
  __builtin_memcpy(&v, &f, 4);
  v += 0x7fffu + ((v >> 16) & 1u);
  return (unsigned short)(v >> 16);
}
__device__ __forceinline__ unsigned short f2bf_hw(float f) {
  __bf16 h = (__bf16)f;
  unsigned short u;
  __builtin_memcpy(&u, &h, 2);
  return u;
}
__device__ __forceinline__ unsigned int pack2(float a, float b) {
  bf16x2 t;
  t[0] = (__bf16)a;
  t[1] = (__bf16)b;
  unsigned int u;
  __builtin_memcpy(&u, &t, 4);
  return u;
}
__device__ __forceinline__ void gl_lds16(const unsigned short* g, unsigned short* l) {
  __builtin_amdgcn_global_load_lds(
      (const __attribute__((address_space(1))) unsigned int*)g,
      (__attribute__((address_space(3))) unsigned int*)l, 16, 0, 0);
}

// ---------------- fused prep: cvt_x + transposes + RoPE LUT ---------------------
__global__ __launch_bounds__(256) void prep(
    const float* __restrict__ x, const float* __restrict__ W_qkv,
    const float* __restrict__ W_out, const int* __restrict__ positions,
    unsigned short* __restrict__ xb,
    unsigned short* __restrict__ Wt_qkv, unsigned short* __restrict__ Wt_out,
    float2* __restrict__ lut) {
  __shared__ float tile[64][65];
  const int bid = blockIdx.x, t = threadIdx.x;
  if (bid < 4096) {  // x fp32 -> bf16
    int i = (bid * 256 + t) * 4;
    float4 v = *reinterpret_cast<const float4*>(x + i);
    ushort4 o;
    o.x = f2bf(v.x); o.y = f2bf(v.y); o.z = f2bf(v.z); o.w = f2bf(v.w);
    *reinterpret_cast<ushort4*>(xb + i) = o;
    return;
  }
  if (bid >= 5120) {  // RoPE LUT: 4096 rows x 32 dpairs
    int idx = (bid - 5120) * 256 + t;
    int m = idx >> 5, p = idx & 31;
    float pos = (float)positions[m];
    float invf = __builtin_amdgcn_exp2f(-(float)(2 * p) * (13.2877124f / 64.0f));
    float rev = pos * invf * 0.15915494f;
    rev -= floorf(rev);
    lut[idx] = make_float2(__builtin_amdgcn_cosf(rev), __builtin_amdgcn_sinf(rev));
    return;
  }
  const float* W; unsigned short* Wt; int Nd, bn, bk;
  if (bid < 4864) {
    int id = bid - 4096; W = W_qkv; Wt = Wt_qkv; Nd = 3072; bn = id % 48; bk = id / 48;
  } else {
    int id = bid - 4864; W = W_out; Wt = Wt_out; Nd = 1024; bn = id % 16; bk = id / 16;
  }
  const int Kd = 1024;
#pragma unroll
  for (int i = 0; i < 16; i++) {
    int idx = i * 256 + t;
    int k = idx >> 6, n = idx & 63;
    tile[k][n] = W[(size_t)(bk * 64 + k) * Nd + bn * 64 + n];
  }
  __syncthreads();
#pragma unroll
  for (int i = 0; i < 16; i++) {
    int idx = i * 256 + t;
    int n = idx >> 6, k = idx & 63;
    Wt[(size_t)(bn * 64 + n) * Kd + bk * 64 + k] = f2bf(tile[k][n]);
  }
}

// ---------------- QKV GEMM 128x128 dbuf + split counted vmcnt -------------------
// grid (24, 32): bn<8 Q (heads 2bn,2bn+1), 8..15 K, 16..23 V.
// 4 waves in 2x2; each wave 64 rows x 64 cols (= one head's columns).
__global__ __launch_bounds__(256, 4) void gemm_qkv(
    const unsigned short* __restrict__ A,
    const unsigned short* __restrict__ Bt,
    const float* __restrict__ qn_w, const float* __restrict__ kn_w,
    const float2* __restrict__ lut,
    unsigned short* __restrict__ Qr,
    unsigned short* __restrict__ Kr,
    unsigned short* __restrict__ Vt, int K) {
  __shared__ __align__(16) unsigned short As[2][128 * 32];
  __shared__ __align__(16) unsigned short Bs[2][128 * 32];
  const int tid = threadIdx.x;
  const int lane = tid & 63, wid = tid >> 6;
  const int quad = lane >> 4, l16 = lane & 15;
  const int wr = wid >> 1, wc = wid & 1;
  const int bn = blockIdx.x, bm = blockIdx.y;
  const unsigned short* Ab = A + (size_t)bm * 128 * K;
  const unsigned short* Bb = Bt + (size_t)bn * 128 * K;

  f32x4 acc[4][4] = {};

  const int c0 = tid, c1 = tid + 256;
  const int ar0 = c0 >> 2, ag0 = ((c0 & 3) ^ ((ar0 >> 1) & 3)) * 8;
  const int ar1 = c1 >> 2, ag1 = ((c1 & 3) ^ ((ar1 >> 1) & 3)) * 8;

  gl_lds16(Ab + (size_t)ar0 * K + ag0, &As[0][c0 * 8]);
  gl_lds16(Ab + (size_t)ar1 * K + ag1, &As[0][c1 * 8]);
  gl_lds16(Bb + (size_t)ar0 * K + ag0, &Bs[0][c0 * 8]);
  gl_lds16(Bb + (size_t)ar1 * K + ag1, &Bs[0][c1 * 8]);

  const int iters = K >> 5;
  for (int it = 0; it < iters; it++) {
    const int cur = it & 1;
    __builtin_amdgcn_s_barrier();
    const bool more = (it + 1 < iters);
    if (more) {
      const int k0 = (it + 1) << 5, nb = cur ^ 1;
      gl_lds16(Ab + (size_t)ar0 * K + k0 + ag0, &As[nb][c0 * 8]);
      gl_lds16(Ab + (size_t)ar1 * K + k0 + ag1, &As[nb][c1 * 8]);
      gl_lds16(Bb + (size_t)ar0 * K + k0 + ag0, &Bs[nb][c0 * 8]);
      gl_lds16(Bb + (size_t)ar1 * K + k0 + ag1, &Bs[nb][c1 * 8]);
      __builtin_amdgcn_sched_barrier(0);
      asm volatile("s_waitcnt vmcnt(6)" ::: "memory");  // cur's A landed
    } else {
      __builtin_amdgcn_sched_barrier(0);
      asm volatile("s_waitcnt vmcnt(2)" ::: "memory");  // cur's A landed (4 in flight)
    }
    __builtin_amdgcn_s_setprio(1);
    const unsigned short* Ac = As[cur];
    const unsigned short* Bc = Bs[cur];
    bf16x8 af[4], bfr[4];
#pragma unroll
    for (int i = 0; i < 4; i++) {
      int m = wr * 64 + i * 16 + l16;
      af[i] = *reinterpret_cast<const bf16x8*>(&Ac[m * 32 + ((quad ^ ((m >> 1) & 3)) * 8)]);
    }
    if (more) {
      asm volatile("s_waitcnt vmcnt(4)" ::: "memory");  // cur's B landed
    } else {
      asm volatile("s_waitcnt vmcnt(0)" ::: "memory");
    }
#pragma unroll
    for (int j = 0; j < 4; j++) {
      int n = wc * 64 + j * 16 + l16;
      bfr[j] = *reinterpret_cast<const bf16x8*>(&Bc[n * 32 + ((quad ^ ((n >> 1) & 3)) * 8)]);
    }
#pragma unroll
    for (int i = 0; i < 4; i++)
#pragma unroll
      for (int j = 0; j < 4; j++)
        acc[i][j] = __builtin_amdgcn_mfma_f32_16x16x32_bf16(af[i], bfr[j], acc[i][j], 0, 0, 0);
    __builtin_amdgcn_s_setprio(0);
  }

  const int sec = bn >> 3;
  const int h = (bn & 7) * 2 + wc;
  const int b = bm >> 4;
  if (sec < 2) {
    // -------- fused LN + RoPE (rows wave-local; 16 rows/thread) --------
    const float* gw = sec ? kn_w : qn_w;
    unsigned short* dst = sec ? Kr : Qr;
    const float oscale = sec ? 1.0f : QSCALE;  // Q pre-scaled for attn's exp2
    float w4[4];
#pragma unroll
    for (int j = 0; j < 4; j++) w4[j] = gw[h * 64 + j * 16 + l16];
#pragma unroll
    for (int i = 0; i < 4; i++)
#pragma unroll
      for (int r = 0; r < 4; r++) {
        int m = bm * 128 + wr * 64 + i * 16 + quad * 4 + r;  // b*2048 + l
        int l = m & 2047;
        const float2* lrow = lut + m * 32;
        float2 cs4[4];
#pragma unroll
        for (int j = 0; j < 4; j++) cs4[j] = lrow[j * 8 + (l16 >> 1)];
        float sum = acc[i][0][r] + acc[i][1][r] + acc[i][2][r] + acc[i][3][r];
        float sq = acc[i][0][r] * acc[i][0][r] + acc[i][1][r] * acc[i][1][r] +
                   acc[i][2][r] * acc[i][2][r] + acc[i][3][r] * acc[i][3][r];
#pragma unroll
        for (int off = 1; off < 16; off <<= 1) {
          sum += __shfl_xor(sum, off);
          sq += __shfl_xor(sq, off);
        }
        float mu = sum * (1.0f / 64.0f);
        float var = sq * (1.0f / 64.0f) - mu * mu;
        float rs = rsqrtf(fmaxf(var, 0.0f) + 1e-6f);
#pragma unroll
        for (int j = 0; j < 4; j++) {
          float y = (acc[i][j][r] - mu) * rs * w4[j];
          float p = __shfl_xor(y, 1);
          float o = (l16 & 1) ? (y * cs4[j].x + p * cs4[j].y)
                              : (y * cs4[j].x - p * cs4[j].y);
          dst[((size_t)(b * 16 + h) * 2048 + l) * 64 + j * 16 + l16] = f2bf(o * oscale);
        }
      }
  } else {
    // -------- V: permuted scatter, packed 4-r uint2 stores --------
    // Contract with attn: within each 32-key group, actual row
    // (i&1)*16 + quad*4 + r is stored at quad*8 + (i&1)*4 + r.
#pragma unroll
    for (int i = 0; i < 4; i++) {
      int lp = (bm * 128 + wr * 64 + (i >> 1) * 32 + quad * 8 + (i & 1) * 4) & 2047;
#pragma unroll
      for (int j = 0; j < 4; j++) {
        int d = j * 16 + l16;
        uint2 v;
        v.x = pack2(acc[i][j][0], acc[i][j][1]);
        v.y = pack2(acc[i][j][2], acc[i][j][3]);
        *reinterpret_cast<uint2*>(&Vt[((size_t)(b * 16 + h) * 64 + d) * 2048 + lp]) = v;
      }
    }
  }
}

// ---------------- Flash attention: 4 waves x 64 q-rows, split waits -------------
// vmcnt(12): cur's K landed -> QK^T + softmax + pack run while cur's V loads
// complete; vmcnt(8) before PV.
__global__ __launch_bounds__(256, 2) void attn_kernel(
    const unsigned short* __restrict__ Q,
    const unsigned short* __restrict__ K,
    const unsigned short* __restrict__ Vt,
    unsigned short* __restrict__ O) {
  __shared__ __align__(16) unsigned short Ks[2][2][64 * 64];  // [half][buf] 32KB
  __shared__ __align__(16) unsigned short Vs[2][2][64 * 64];  // 32KB

  int bid = blockIdx.x;
  int id = (bid & 7) * 64 + (bid >> 3);  // bijective XCD swizzle (512 % 8 == 0)
  const int qt = id & 15; id >>= 4;
  const int h = id & 15;  const int b = id >> 4;
  const int tid = threadIdx.x;
  const int lane = tid & 63, wid = tid >> 6;
  const int half = wid >> 1, wg = wid & 1;
  const int quad = lane >> 4, l16 = lane & 15;

  const unsigned short* Qb = Q + (size_t)(b * 16 + h) * 2048 * 64;
  const unsigned short* Kb = K + (size_t)(b * 16 + h) * 2048 * 64;
  const unsigned short* Vb = Vt + (size_t)(b * 16 + h) * 64 * 2048;

  const int qbase = qt * 128 + wg * 64;
  bf16x8 qf[4][2];
#pragma unroll
  for (int g = 0; g < 4; g++)
#pragma unroll
    for (int d = 0; d < 2; d++)
      qf[g][d] = *reinterpret_cast<const bf16x8*>(
          &Qb[(size_t)(qbase + g * 16 + l16) * 64 + d * 32 + quad * 8]);

  f32x4 o[4][4] = {};
  float lsum[4] = {0.f, 0.f, 0.f, 0.f};

  const int ltid = tid & 127;
  int cs[4], rs[4], gsw[4];
#pragma unroll
  for (int j = 0; j < 4; j++) {
    cs[j] = ltid + j * 128;
    rs[j] = cs[j] >> 3;
    gsw[j] = ((cs[j] & 7) ^ (rs[j] & 7)) * 8;
  }
  const int kb0 = half * 1024;

#pragma unroll
  for (int j = 0; j < 4; j++)
    gl_lds16(&Kb[(size_t)(kb0 + rs[j]) * 64 + gsw[j]], &Ks[half][0][cs[j] * 8]);
#pragma unroll
  for (int j = 0; j < 4; j++)
    gl_lds16(&Vb[(size_t)rs[j] * 2048 + kb0 + gsw[j]], &Vs[half][0][cs[j] * 8]);

  for (int kt = 0; kt < 16; kt++) {
    const int cur = kt & 1;
    __builtin_amdgcn_s_barrier();
    const bool more = (kt + 1 < 16);
    if (more) {
      const int ko = kb0 + (kt + 1) * 64, nb = cur ^ 1;
#pragma unroll
      for (int j = 0; j < 4; j++)
        gl_lds16(&Kb[(size_t)(ko + rs[j]) * 64 + gsw[j]], &Ks[half][nb][cs[j] * 8]);
#pragma unroll
      for (int j = 0; j < 4; j++)
        gl_lds16(&Vb[(size_t)rs[j] * 2048 + ko + gsw[j]], &Vs[half][nb][cs[j] * 8]);
      __builtin_amdgcn_sched_barrier(0);
      asm volatile("s_waitcnt vmcnt(12)" ::: "memory");  // cur's K landed
    } else {
      __builtin_amdgcn_sched_barrier(0);
      asm volatile("s_waitcnt vmcnt(4)" ::: "memory");   // cur's K landed (8 in flight)
    }
    const unsigned short* Kc = Ks[half][cur];
    const unsigned short* Vc = Vs[half][cur];

    __builtin_amdgcn_s_setprio(1);
    // ---- QK^T: kf read once per kg, consumed by all 4 q-groups ----
    f32x4 s4[4][4] = {};  // [g][kg]
#pragma unroll
    for (int kg = 0; kg < 4; kg++) {
      int row = kg * 16 + l16;
      bf16x8 kf0 = *reinterpret_cast<const bf16x8*>(
          &Kc[row * 64 + ((quad ^ (row & 7)) * 8)]);
      bf16x8 kf1 = *reinterpret_cast<const bf16x8*>(
          &Kc[row * 64 + (((4 + quad) ^ (row & 7)) * 8)]);
#pragma unroll
      for (int g = 0; g < 4; g++) {
        s4[g][kg] = __builtin_amdgcn_mfma_f32_16x16x32_bf16(kf0, qf[g][0], s4[g][kg], 0, 0, 0);
        s4[g][kg] = __builtin_amdgcn_mfma_f32_16x16x32_bf16(kf1, qf[g][1], s4[g][kg], 0, 0, 0);
      }
    }
    // ---- exp2 + VALU lsum + bf16 pack (covers cur's V-load tail) ----
    union u32x4v { unsigned int u[4]; bf16x8 v; };
    u32x4v pa[4][2];
#pragma unroll
    for (int g = 0; g < 4; g++) {
      float pv[4][4];
#pragma unroll
      for (int kg = 0; kg < 4; kg++)
#pragma unroll
        for (int r = 0; r < 4; r++) {
          float e = __builtin_amdgcn_exp2f(s4[g][kg][r]);  // Q pre-scaled 0.125*log2e
          pv[kg][r] = e;
          lsum[g] += e;
        }
#pragma unroll
      for (int c = 0; c < 2; c++) {
        pa[g][c].u[0] = pack2(pv[c * 2][0], pv[c * 2][1]);
        pa[g][c].u[1] = pack2(pv[c * 2][2], pv[c * 2][3]);
        pa[g][c].u[2] = pack2(pv[c * 2 + 1][0], pv[c * 2 + 1][1]);
        pa[g][c].u[3] = pack2(pv[c * 2 + 1][2], pv[c * 2 + 1][3]);
      }
    }
    if (more) {
      asm volatile("s_waitcnt vmcnt(8)" ::: "memory");  // cur's V landed
    } else {
      asm volatile("s_waitcnt vmcnt(0)" ::: "memory");
    }
    // ---- PV: vfr read once per (c,i), consumed by all 4 q-groups ----
#pragma unroll
    for (int c = 0; c < 2; c++)
#pragma unroll
      for (int i = 0; i < 4; i++) {
        int row = i * 16 + l16;
        bf16x8 vfr = *reinterpret_cast<const bf16x8*>(
            &Vc[row * 64 + (((c * 4 + quad) ^ (row & 7)) * 8)]);
#pragma unroll
        for (int g = 0; g < 4; g++)
          o[g][i] = __builtin_amdgcn_mfma_f32_16x16x32_bf16(pa[g][c].v, vfr, o[g][i], 0, 0, 0);
      }
    __builtin_amdgcn_s_setprio(0);
  }

  // lsum currently per-lane partial over this wave's P columns; reduce to per-q.
#pragma unroll
  for (int g = 0; g < 4; g++) {
    lsum[g] += __shfl_xor(lsum[g], 16);
    lsum[g] += __shfl_xor(lsum[g], 32);
  }

  __syncthreads();
  float* Om = (float*)&Ks[0][0][0];  // 128x64 fp32 = 32 KB
  float* Lm = (float*)&Vs[0][0][0];
  if (half == 0) {
#pragma unroll
    for (int g = 0; g < 4; g++) {
#pragma unroll
      for (int i = 0; i < 4; i++)
#pragma unroll
        for (int r = 0; r < 4; r++)
          Om[(wg * 64 + g * 16 + quad * 4 + r) * 64 + i * 16 + l16] = o[g][i][r];
      if (quad == 0) Lm[wg * 64 + g * 16 + l16] = lsum[g];
    }
  }
  __syncthreads();
  if (half == 1) {
#pragma unroll
    for (int g = 0; g < 4; g++) {
      float lt = lsum[g] + Lm[wg * 64 + g * 16 + l16];
#pragma unroll
      for (int r = 0; r < 4; r++) {
        float inv = 1.0f / __shfl(lt, quad * 4 + r);
        int q = qbase + g * 16 + quad * 4 + r;
#pragma unroll
        for (int i = 0; i < 4; i++) {
          float sum = o[g][i][r] + Om[(wg * 64 + g * 16 + quad * 4 + r) * 64 + i * 16 + l16];
          O[((size_t)(b * 2048 + q)) * 1024 + h * 64 + i * 16 + l16] = f2bf_hw(sum * inv);
        }
      }
    }
  }
}

// ---------------- final GEMM 128x64 tiles, BK=64, split waits -------------------
// grid 512 (1-D) with XCD swizzle: id=(bid&7)*64+bid>>3, bm=id>>4, bn=id&15.
__global__ __launch_bounds__(256) void gemm_out(
    const unsigned short* __restrict__ A,
    const unsigned short* __restrict__ Bt,
    float* __restrict__ C, int M, int N, int K) {
  __shared__ __align__(16) unsigned short As[2][128 * 64];
  __shared__ __align__(16) unsigned short Bs[2][64 * 64];
  const int tid = threadIdx.x;
  const int lane = tid & 63, wid = tid >> 6;
  const int quad = lane >> 4, l16 = lane & 15;
  int bid = blockIdx.x;
  int id = (bid & 7) * 64 + (bid >> 3);  // bijective XCD swizzle (512 % 8 == 0)
  const int bn = id & 15, bm = id >> 4;  // consecutive ids share bm (A panel)
  const unsigned short* Ab = A + (size_t)bm * 128 * K;
  const unsigned short* Bb = Bt + (size_t)bn * 64 * K;

  f32x4 acc[2][4] = {};

  int arow[4], asrc[4];
#pragma unroll
  for (int t2 = 0; t2 < 4; t2++) {
    int s = t2 * 256 + tid;
    arow[t2] = s >> 3;
    asrc[t2] = (((s & 7) ^ (arow[t2] & 7)) * 8);
  }
  int brow[2], bsrc[2];
#pragma unroll
  for (int t2 = 0; t2 < 2; t2++) {
    int s = t2 * 256 + tid;
    brow[t2] = s >> 3;
    bsrc[t2] = (((s & 7) ^ (brow[t2] & 7)) * 8);
  }

#pragma unroll
  for (int t2 = 0; t2 < 4; t2++)
    gl_lds16(Ab + (size_t)arow[t2] * K + asrc[t2], &As[0][(t2 * 256 + tid) * 8]);
#pragma unroll
  for (int t2 = 0; t2 < 2; t2++)
    gl_lds16(Bb + (size_t)brow[t2] * K + bsrc[t2], &Bs[0][(t2 * 256 + tid) * 8]);

  const int iters = K >> 6;  // 16
  for (int it = 0; it < iters; it++) {
    const int cur = it & 1;
    __builtin_amdgcn_s_barrier();
    const bool more = (it + 1 < iters);
    if (more) {
      const int k0 = (it + 1) << 6, nb = cur ^ 1;
#pragma unroll
      for (int t2 = 0; t2 < 4; t2++)
        gl_lds16(Ab + (size_t)arow[t2] * K + k0 + asrc[t2], &As[nb][(t2 * 256 + tid) * 8]);
#pragma unroll
      for (int t2 = 0; t2 < 2; t2++)
        gl_lds16(Bb + (size_t)brow[t2] * K + k0 + bsrc[t2], &Bs[nb][(t2 * 256 + tid) * 8]);
      __builtin_amdgcn_sched_barrier(0);
      asm volatile("s_waitcnt vmcnt(8)" ::: "memory");  // cur's A landed
    } else {
      __builtin_amdgcn_sched_barrier(0);
      asm volatile("s_waitcnt vmcnt(2)" ::: "memory");  // cur's A landed (6 in flight)
    }
    __builtin_amdgcn_s_setprio(1);
    const unsigned short* Ac = As[cur];
    const unsigned short* Bc = Bs[cur];
    bf16x8 af[2][2], bfr[4][2];
#pragma unroll
    for (int i = 0; i < 2; i++) {
      int m = wid * 32 + i * 16 + l16;
#pragma unroll
      for (int kk = 0; kk < 2; kk++)
        af[i][kk] = *reinterpret_cast<const bf16x8*>(
            &Ac[(m * 8 + ((kk * 4 + quad) ^ (m & 7))) * 8]);
    }
    if (more) {
      asm volatile("s_waitcnt vmcnt(6)" ::: "memory");  // cur's B landed
    } else {
      asm volatile("s_waitcnt vmcnt(0)" ::: "memory");
    }
#pragma unroll
    for (int j = 0; j < 4; j++) {
      int n = j * 16 + l16;
#pragma unroll
      for (int kk = 0; kk < 2; kk++)
        bfr[j][kk] = *reinterpret_cast<const bf16x8*>(
            &Bc[(n * 8 + ((kk * 4 + quad) ^ (n & 7))) * 8]);
    }
#pragma unroll
    for (int kk = 0; kk < 2; kk++)
#pragma unroll
      for (int i = 0; i < 2; i++)
#pragma unroll
        for (int j = 0; j < 4; j++)
          acc[i][j] = __builtin_amdgcn_mfma_f32_16x16x32_bf16(af[i][kk], bfr[j][kk], acc[i][j], 0, 0, 0);
    __builtin_amdgcn_s_setprio(0);
  }
#pragma unroll
  for (int i = 0; i < 2; i++)
#pragma unroll
    for (int j = 0; j < 4; j++)
#pragma unroll
      for (int r = 0; r < 4; r++) {
        int m = bm * 128 + wid * 32 + i * 16 + quad * 4 + r;
        int n = bn * 64 + j * 16 + l16;
        C[(size_t)m * N + n] = acc[i][j][r];
      }
}

extern "C" void kernel_launch(void* const* d_in, const int* in_sizes, int n_in,
                              void* d_out, int out_size, void* d_ws, size_t ws_size,
                              hipStream_t stream) {
  (void)in_sizes; (void)n_in; (void)out_size; (void)ws_size;
  const float* x     = (const float*)d_in[0];
  const int*   pos   = (const int*)d_in[2];
  const float* W_qkv = (const float*)d_in[3];
  const float* W_out = (const float*)d_in[4];
  const float* qn_w  = (const float*)d_in[5];
  const float* kn_w  = (const float*)d_in[6];
  float*       out   = (float*)d_out;

  char* ws = (char*)d_ws;
  unsigned short* xb     = (unsigned short*)(ws);
  unsigned short* Qr     = (unsigned short*)(ws + 8388608);
  unsigned short* Kr     = (unsigned short*)(ws + 16777216);
  unsigned short* Vt     = (unsigned short*)(ws + 25165824);
  unsigned short* Wt_qkv = (unsigned short*)(ws + 33554432);
  unsigned short* Wt_out = (unsigned short*)(ws + 39845888);
  float2*         lut    = (float2*)(ws + 41943040);
  unsigned short* attn_o = xb;

  prep<<<5632, 256, 0, stream>>>(x, W_qkv, W_out, pos, xb, Wt_qkv, Wt_out, lut);
  gemm_qkv<<<dim3(24, 32), 256, 0, stream>>>(xb, Wt_qkv, qn_w, kn_w, lut, Qr, Kr, Vt, 1024);
  attn_kernel<<<512, 256, 0, stream>>>(Qr, Kr, Vt, attn_o);
  gemm_out<<<512, 256, 0, stream>>>(attn_o, Wt_out, out, 4096, 1024, 1024);
}